// Round 7
// baseline (253.222 us; speedup 1.0000x reference)
//
#include <hip/hip_runtime.h>
#include <hip/hip_bf16.h>

constexpr int Bb = 4;
constexpr int Nn = 2048;
constexpr int DX = 2048;
constexpr int GD = 1024;   // gate width
constexpr int DH = 256;    // per-head width
constexpr int BM = 128, BD = 128, BK = 32;

typedef short short8v __attribute__((ext_vector_type(8)));
typedef short short4v __attribute__((ext_vector_type(4)));
typedef float f32x4   __attribute__((ext_vector_type(4)));

static __device__ __forceinline__ short f2bf(float f) {
    return __builtin_bit_cast(short, __float2bfloat16(f));   // RNE
}

// one wave per row: mean / rstd of gate half -> interleaved float2 {mu, rstd}
__global__ __launch_bounds__(256) void ln_stats_kernel(const float* __restrict__ x,
                                                       float2* __restrict__ mr) {
    int t = threadIdx.x;
    int row = blockIdx.x * 4 + (t >> 6);
    int lane = t & 63;
    const float4* xr = reinterpret_cast<const float4*>(x + (size_t)row * DX + GD);
    float s = 0.f, ss = 0.f;
#pragma unroll
    for (int q = 0; q < 4; ++q) {
        float4 v = xr[q * 64 + lane];
        s  += v.x + v.y + v.z + v.w;
        ss += v.x*v.x + v.y*v.y + v.z*v.z + v.w*v.w;
    }
#pragma unroll
    for (int off = 32; off >= 1; off >>= 1) {
        s  += __shfl_down(s,  off, 64);
        ss += __shfl_down(ss, off, 64);
    }
    if (lane == 0) {
        float m   = s * (1.f / GD);
        float var = ss * (1.f / GD) - m * m;
        mr[row] = make_float2(m, rsqrtf(var + 1e-5f));
    }
}

__global__ __launch_bounds__(256, 3) void sgu_mfma_kernel(
    const float* __restrict__ x, const float* __restrict__ w,
    const float* __restrict__ bias, const float* __restrict__ gamma,
    const float* __restrict__ beta, const float2* __restrict__ mr,
    float* __restrict__ out)
{
    __shared__ __align__(16) short Ws[2][BM * BK];   // [m-row 128][k 32] bf16, slot-XOR swizzled
    __shared__ __align__(16) short Gs[2][BD * BK];   // [c-row 128][k 32] bf16 (TRANSPOSED), same swizzle
    __shared__ __align__(16) float2 MR[Nn];          // {mu, rstd} per n, staged once per block

    const int t  = threadIdx.x;
    const int bx = blockIdx.x;              // dc(2) | h(4) | b(4)
    const int dc = bx & 1;
    const int h  = (bx >> 1) & 3;
    const int b  = bx >> 3;
    const int y  = blockIdx.y;              // heavy-first, pair-balanced m order
    const int mt = (y < 8) ? (15 - 2 * y) : ((y - 8) * 2);
    const int m0 = mt * BM;
    const int cb = h * DH + dc * BD;        // channel base in [0,1024)
    const int nk = 4 * mt + 4;              // causal k-tiles

    const int lane = t & 63;
    const int wv = t >> 6;
    const int wm = wv >> 1, wc = wv & 1;    // 2x2 wave grid, 64x64 per wave
    const int g  = lane >> 4;               // k-slice group
    const int lr = lane & 15;

    // staging roles
    const int sw_row = t >> 1;              // W row 0..127
    const int sw_kh  = t & 1;               // W k-half (16 k)
    const int sg_c4  = (t & 31) * 4;        // G channel quad base 0..124
    const int sg_k4  = (t >> 5) * 4;        // G k quad base 0..28

    const float* xb   = x + (size_t)b * Nn * DX;
    const float* wrow = w + ((size_t)h * Nn + m0 + sw_row) * Nn + sw_kh * 16;
    const float* gsrc = xb + GD + cb + sg_c4;
    const float2* mrb = mr + b * Nn;

    // per-thread gamma/beta for the 4 staged channels
    float4 gmv = *reinterpret_cast<const float4*>(gamma + cb + sg_c4);
    float4 btv = *reinterpret_cast<const float4*>(beta  + cb + sg_c4);
    const float gmc[4] = {gmv.x, gmv.y, gmv.z, gmv.w};
    const float btc[4] = {btv.x, btv.y, btv.z, btv.w};

    f32x4 acc[4][4] = {};
    float4 wreg[4];            // W: 16 contiguous k for row sw_row
    float4 greg[4];            // G: [j] = 4 channels (c4..c4+3) at k = sg_k4+j

    auto LOADT = [&](int kt) {
        const int n0 = kt * BK;
#pragma unroll
        for (int q = 0; q < 4; ++q)
            wreg[q] = *reinterpret_cast<const float4*>(wrow + n0 + q * 4);
#pragma unroll
        for (int j = 0; j < 4; ++j)
            greg[j] = *reinterpret_cast<const float4*>(gsrc + (size_t)(n0 + sg_k4 + j) * DX);
    };

    auto STAGE = [&](int buf, int kt) {
        const int n0 = kt * BK;
        // --- W: tril mask + cvt, two swizzled b128 writes ---
        const int m = m0 + sw_row;
        short8v wlo, whi;
#pragma unroll
        for (int q = 0; q < 4; ++q) {
            float vv[4] = {wreg[q].x, wreg[q].y, wreg[q].z, wreg[q].w};
#pragma unroll
            for (int e = 0; e < 4; ++e) {
                int i = q * 4 + e;
                int n = n0 + sw_kh * 16 + i;
                short bfv = f2bf((n <= m) ? vv[e] : 0.f);
                if (i < 8) wlo[i] = bfv; else whi[i - 8] = bfv;
            }
        }
        char* wl = (char*)&Ws[buf][0];
        unsigned wb = (unsigned)(sw_row * 64 + sw_kh * 32);
        unsigned sz = ((unsigned)(sw_row >> 1) & 3u) << 4;
        *reinterpret_cast<short8v*>(wl + ((wb)      ^ sz)) = wlo;
        *reinterpret_cast<short8v*>(wl + ((wb + 16) ^ sz)) = whi;
        // --- G (transposed): LN + cvt; 4 channels x 4 k -> 4 swizzled b64 writes ---
        float muk[4], rsk[4];
        {
            f32x4 p0 = *reinterpret_cast<const f32x4*>(&MR[n0 + sg_k4]);
            f32x4 p1 = *reinterpret_cast<const f32x4*>(&MR[n0 + sg_k4 + 2]);
            muk[0] = p0[0]; rsk[0] = p0[1]; muk[1] = p0[2]; rsk[1] = p0[3];
            muk[2] = p1[0]; rsk[2] = p1[1]; muk[3] = p1[2]; rsk[3] = p1[3];
        }
        float gv[4][4];        // [j][cc]
        gv[0][0]=greg[0].x; gv[0][1]=greg[0].y; gv[0][2]=greg[0].z; gv[0][3]=greg[0].w;
        gv[1][0]=greg[1].x; gv[1][1]=greg[1].y; gv[1][2]=greg[1].z; gv[1][3]=greg[1].w;
        gv[2][0]=greg[2].x; gv[2][1]=greg[2].y; gv[2][2]=greg[2].z; gv[2][3]=greg[2].w;
        gv[3][0]=greg[3].x; gv[3][1]=greg[3].y; gv[3][2]=greg[3].z; gv[3][3]=greg[3].w;
        char* glp = (char*)&Gs[buf][0];
#pragma unroll
        for (int cc = 0; cc < 4; ++cc) {
            short4v pk;
#pragma unroll
            for (int j = 0; j < 4; ++j)
                pk[j] = f2bf((gv[j][cc] - muk[j]) * rsk[j] * gmc[cc] + btc[cc]);
            int c = sg_c4 + cc;
            unsigned off = (unsigned)(c * 64 + sg_k4 * 2);
            off ^= ((unsigned)(c >> 1) & 3u) << 4;
            *reinterpret_cast<short4v*>(glp + off) = pk;
        }
    };

    auto COMPUTE = [&](int buf) {
        const char* wl  = (const char*)&Ws[buf][0];
        const char* glp = (const char*)&Gs[buf][0];
        short8v af[4], bfr[4];
#pragma unroll
        for (int fi = 0; fi < 4; ++fi) {
            int row = wm * 64 + fi * 16 + lr;
            unsigned off = (unsigned)(row * 64 + g * 16);
            off ^= ((unsigned)(row >> 1) & 3u) << 4;
            af[fi] = *reinterpret_cast<const short8v*>(wl + off);
        }
#pragma unroll
        for (int fj = 0; fj < 4; ++fj) {
            int c = wc * 64 + fj * 16 + lr;
            unsigned off = (unsigned)(c * 64 + g * 16);
            off ^= ((unsigned)(c >> 1) & 3u) << 4;
            bfr[fj] = *reinterpret_cast<const short8v*>(glp + off);
        }
#pragma unroll
        for (int fi = 0; fi < 4; ++fi)
#pragma unroll
            for (int fj = 0; fj < 4; ++fj)
                acc[fi][fj] = __builtin_amdgcn_mfma_f32_16x16x32_bf16(
                    af[fi], bfr[fj], acc[fi][fj], 0, 0, 0);
    };

    // block prologue: stage {mu,rstd} table (only the causal n-range), issue tile-0 loads
    const int nstage = nk * BK;             // = m0 + 128
    for (int i = t; i < nstage; i += 256)
        MR[i] = mrb[i];
    LOADT(0);
    __syncthreads();                        // MR visible before first STAGE
    STAGE(0, 0);
    __syncthreads();

    int cur = 0;
    for (int kt = 0; kt < nk; ++kt) {
        const bool more = (kt + 1 < nk);
        if (more) LOADT(kt + 1);            // issue early — hides under MFMA
        COMPUTE(cur);
        if (more) STAGE(cur ^ 1, kt + 1);   // write late
        __syncthreads();
        cur ^= 1;
    }

    // epilogue: (+bias) * res
#pragma unroll
    for (int fi = 0; fi < 4; ++fi) {
#pragma unroll
        for (int r = 0; r < 4; ++r) {
            int m = m0 + wm * 64 + fi * 16 + g * 4 + r;
            float bv = bias[h * Nn + m];
            const float* resrow = xb + (size_t)m * DX + cb;
            float* orow = out + ((size_t)b * Nn + m) * GD + cb;
#pragma unroll
            for (int fj = 0; fj < 4; ++fj) {
                int c = wc * 64 + fj * 16 + lr;
                orow[c] = (acc[fi][fj][r] + bv) * resrow[c];
            }
        }
    }
}

extern "C" void kernel_launch(void* const* d_in, const int* in_sizes, int n_in,
                              void* d_out, int out_size, void* d_ws, size_t ws_size,
                              hipStream_t stream) {
    const float* x     = (const float*)d_in[0];
    const float* w     = (const float*)d_in[1];
    const float* bias  = (const float*)d_in[2];
    const float* gamma = (const float*)d_in[3];
    const float* beta  = (const float*)d_in[4];
    float* out  = (float*)d_out;
    float2* mrw = (float2*)d_ws;           // B*N float2 {mu, rstd} (64 KB)

    ln_stats_kernel<<<Bb * Nn / 4, 256, 0, stream>>>(x, mrw);

    dim3 grid(32, 16, 1);                  // x: dc|h|b, y: balanced m-tile order
    sgu_mfma_kernel<<<grid, 256, 0, stream>>>(x, w, bias, gamma, beta, mrw, out);
}

// Round 8
// 217.626 us; speedup vs baseline: 1.1636x; 1.1636x over previous
//
#include <hip/hip_runtime.h>
#include <hip/hip_bf16.h>

// CausalSGU restructure: one-shot bf16 pre-passes -> pure global_load_lds MFMA matmul.
// ws layout: [0,64K) mu/rstd float2 | [64K, 64K+16M) Gt bf16 tiles | +32M Wt bf16 tiles.
// Tile format (8KB = 512 slots x 16B): slot s -> row r=s>>2, holds k=((s&3)^((r>>1)&3))*8..+8
// (i.e. the exact XOR-swizzled LDS image; both-sides-or-neither rule m173/m104).

constexpr int Bb = 4;
constexpr int Nn = 2048;
constexpr int DX = 2048;
constexpr int GD = 1024;   // gate width
constexpr int DH = 256;    // per-head width

typedef short short8v __attribute__((ext_vector_type(8)));
typedef float f32x4   __attribute__((ext_vector_type(4)));

static __device__ __forceinline__ short f2bf(float f) {
    return __builtin_bit_cast(short, __float2bfloat16(f));   // RNE
}

static __device__ __forceinline__ void gll16(const void* g, void* l) {
    __builtin_amdgcn_global_load_lds(
        (const __attribute__((address_space(1))) void*)g,
        (__attribute__((address_space(3))) void*)l, 16, 0, 0);
}

// --- kernel 1: per-row mean/rstd of gate half -> float2 {mu, rstd} ---
__global__ __launch_bounds__(256) void ln_stats_kernel(const float* __restrict__ x,
                                                       float2* __restrict__ mr) {
    int t = threadIdx.x;
    int row = blockIdx.x * 4 + (t >> 6);
    int lane = t & 63;
    const float4* xr = reinterpret_cast<const float4*>(x + (size_t)row * DX + GD);
    float s = 0.f, ss = 0.f;
#pragma unroll
    for (int q = 0; q < 4; ++q) {
        float4 v = xr[q * 64 + lane];
        s  += v.x + v.y + v.z + v.w;
        ss += v.x*v.x + v.y*v.y + v.z*v.z + v.w*v.w;
    }
#pragma unroll
    for (int off = 32; off >= 1; off >>= 1) {
        s  += __shfl_down(s,  off, 64);
        ss += __shfl_down(ss, off, 64);
    }
    if (lane == 0) {
        float m   = s * (1.f / GD);
        float var = ss * (1.f / GD) - m * m;
        mr[row] = make_float2(m, rsqrtf(var + 1e-5f));
    }
}

// --- kernel 2: W fp32 -> Wt bf16 tiles, tril baked in. block=(h*16+mt, kt) ---
__global__ __launch_bounds__(256) void wcvt_kernel(const float* __restrict__ w,
                                                   short* __restrict__ wt) {
    const int hm = blockIdx.x;          // h*16 + mt
    const int kt = blockIdx.y;          // 0..63
    const int mt = hm & 15, h = hm >> 4;
    if (kt > 4 * mt + 3) return;        // upper-triangular tile: never read
    const int t = threadIdx.x;
    const int m0 = mt * 128, n0 = kt * 32;
    short* tile = wt + ((size_t)hm * 64 + kt) * 4096;
#pragma unroll
    for (int j = 0; j < 2; ++j) {
        int s  = 2 * t + j;
        int r  = s >> 2;
        int k8 = (s & 3) ^ ((r >> 1) & 3);
        const float* src = w + (size_t)(h * Nn + m0 + r) * Nn + n0 + k8 * 8;
        float4 a = *reinterpret_cast<const float4*>(src);
        float4 c = *reinterpret_cast<const float4*>(src + 4);
        const int m = m0 + r, nb0 = n0 + k8 * 8;
        float av[8] = {a.x, a.y, a.z, a.w, c.x, c.y, c.z, c.w};
        short8v o;
#pragma unroll
        for (int e = 0; e < 8; ++e) o[e] = f2bf((nb0 + e) <= m ? av[e] : 0.f);
        *reinterpret_cast<short8v*>(tile + s * 8) = o;
    }
}

// --- kernel 3: gate -> LN -> bf16, transposed to [c][n] tiles. block=(nb, cblk, b) ---
__global__ __launch_bounds__(256) void gcvt_kernel(const float* __restrict__ x,
                                                   const float* __restrict__ gamma,
                                                   const float* __restrict__ beta,
                                                   const float2* __restrict__ mr,
                                                   short* __restrict__ gt) {
    __shared__ short T[128 * 136];      // [c][n] bf16, pitch 136 (conflict pad)
    const int nb = blockIdx.x, cblk = blockIdx.y, b = blockIdx.z;
    const int t = threadIdx.x;
    const int n0b = nb * 128, c0 = cblk * 128;
    const int c4 = (t & 31) * 4, rg = t >> 5;

    const float* src = x + (size_t)b * Nn * DX + GD + c0 + c4;
    float4 gm = *reinterpret_cast<const float4*>(gamma + c0 + c4);
    float4 bt = *reinterpret_cast<const float4*>(beta  + c0 + c4);
    const float2* mrb = mr + b * Nn + n0b;

#pragma unroll
    for (int i = 0; i < 16; ++i) {
        int n = i * 8 + rg;
        float2 ms = mrb[n];
        float4 v  = *reinterpret_cast<const float4*>(src + (size_t)(n0b + n) * DX);
        T[(c4 + 0) * 136 + n] = f2bf((v.x - ms.x) * ms.y * gm.x + bt.x);
        T[(c4 + 1) * 136 + n] = f2bf((v.y - ms.x) * ms.y * gm.y + bt.y);
        T[(c4 + 2) * 136 + n] = f2bf((v.z - ms.x) * ms.y * gm.z + bt.z);
        T[(c4 + 3) * 136 + n] = f2bf((v.w - ms.x) * ms.y * gm.w + bt.w);
    }
    __syncthreads();
    // emit 4 swizzled 8KB tiles (kt = nb*4 .. nb*4+3)
#pragma unroll
    for (int kq = 0; kq < 4; ++kq) {
        short* tile = gt + ((size_t)(b * 8 + cblk) * 64 + (nb * 4 + kq)) * 4096;
#pragma unroll
        for (int j = 0; j < 2; ++j) {
            int s  = 2 * t + j;
            int c  = s >> 2;
            int n8 = (s & 3) ^ ((c >> 1) & 3);
            short8v v = *reinterpret_cast<const short8v*>(&T[c * 136 + kq * 32 + n8 * 8]);
            *reinterpret_cast<short8v*>(tile + s * 8) = v;
        }
    }
}

// --- kernel 4: causal MFMA matmul + fused bias/res epilogue ---
__global__ __launch_bounds__(256, 3) void sgu_mfma_kernel(
    const float* __restrict__ x, const short* __restrict__ wt,
    const short* __restrict__ gt, const float* __restrict__ bias,
    float* __restrict__ out)
{
    __shared__ __align__(16) short WS[2][4096];
    __shared__ __align__(16) short GS[2][4096];

    const int t  = threadIdx.x;
    const int bx = blockIdx.x;              // dc(2) | h(4) | b(4)
    const int dc = bx & 1;
    const int h  = (bx >> 1) & 3;
    const int b  = bx >> 3;
    const int y  = blockIdx.y;              // mt order: pairs (y,y+8) sum to const work
    const int mt = (y < 8) ? (15 - 2 * y) : ((y - 8) * 2);
    const int m0 = mt * 128;
    const int cb = h * DH + dc * 128;
    const int nk = 4 * mt + 4;              // causal k-tiles

    const int lane = t & 63;
    const int wv = t >> 6;
    const int wm = wv >> 1, wc = wv & 1;    // 2x2 wave grid, 64x64 per wave
    const int g  = lane >> 4;               // k-slice group
    const int lr = lane & 15;

    const char* wtb = (const char*)wt + ((size_t)(h * 16 + mt) * 64) * 8192;
    const char* gtb = (const char*)gt + ((size_t)(b * 8 + h * 2 + dc) * 64) * 8192;
    const int soff = wv * 2048 + lane * 16; // per-lane src byte offset within tile

    f32x4 acc[4][4] = {};

    auto STAGE = [&](int buf, int kt) {
        const char* ws = wtb + (size_t)kt * 8192 + soff;
        const char* gs = gtb + (size_t)kt * 8192 + soff;
        short* wd = &WS[buf][wv * 1024];    // wave-uniform LDS base
        short* gd = &GS[buf][wv * 1024];
        gll16(ws,        wd);
        gll16(ws + 1024, wd + 512);
        gll16(gs,        gd);
        gll16(gs + 1024, gd + 512);
    };

    auto COMPUTE = [&](int buf) {
        const char* wl = (const char*)&WS[buf][0];
        const char* gl = (const char*)&GS[buf][0];
        short8v af[4], bf[4];
#pragma unroll
        for (int fi = 0; fi < 4; ++fi) {
            int row = wm * 64 + fi * 16 + lr;
            unsigned off = (unsigned)(row * 64 + g * 16);
            off ^= ((unsigned)(row >> 1) & 3u) << 4;
            af[fi] = *reinterpret_cast<const short8v*>(wl + off);
        }
#pragma unroll
        for (int fj = 0; fj < 4; ++fj) {
            int c = wc * 64 + fj * 16 + lr;
            unsigned off = (unsigned)(c * 64 + g * 16);
            off ^= ((unsigned)(c >> 1) & 3u) << 4;
            bf[fj] = *reinterpret_cast<const short8v*>(gl + off);
        }
#pragma unroll
        for (int fi = 0; fi < 4; ++fi)
#pragma unroll
            for (int fj = 0; fj < 4; ++fj)
                acc[fi][fj] = __builtin_amdgcn_mfma_f32_16x16x32_bf16(
                    af[fi], bf[fj], acc[fi][fj], 0, 0, 0);
    };

    STAGE(0, 0);
    __syncthreads();                        // drains vmcnt -> tile 0 visible
    int cur = 0;
    for (int kt = 0; kt < nk; ++kt) {
        if (kt + 1 < nk) STAGE(cur ^ 1, kt + 1);  // async prefetch next tile
        COMPUTE(cur);
        __syncthreads();                    // drain gll + barrier
        cur ^= 1;
    }

    const float* xb = x + (size_t)b * Nn * DX;
#pragma unroll
    for (int fi = 0; fi < 4; ++fi) {
#pragma unroll
        for (int r = 0; r < 4; ++r) {
            int m = m0 + wm * 64 + fi * 16 + g * 4 + r;
            float bv = bias[h * Nn + m];
            const float* resrow = xb + (size_t)m * DX + cb;
            float* orow = out + ((size_t)b * Nn + m) * GD + cb;
#pragma unroll
            for (int fj = 0; fj < 4; ++fj) {
                int c = wc * 64 + fj * 16 + lr;
                orow[c] = (acc[fi][fj][r] + bv) * resrow[c];
            }
        }
    }
}

extern "C" void kernel_launch(void* const* d_in, const int* in_sizes, int n_in,
                              void* d_out, int out_size, void* d_ws, size_t ws_size,
                              hipStream_t stream) {
    const float* x     = (const float*)d_in[0];
    const float* w     = (const float*)d_in[1];
    const float* bias  = (const float*)d_in[2];
    const float* gamma = (const float*)d_in[3];
    const float* beta  = (const float*)d_in[4];
    float* out = (float*)d_out;

    const size_t MR_BYTES = 64 * 1024;
    const size_t GT_BYTES = (size_t)16 * 1024 * 1024;
    const size_t WT_BYTES = (size_t)32 * 1024 * 1024;
    if (ws_size < MR_BYTES + GT_BYTES + WT_BYTES) return;  // loud fail: learn ws_size

    float2* mrw = (float2*)d_ws;
    short*  gtw = (short*)((char*)d_ws + MR_BYTES);
    short*  wtw = (short*)((char*)d_ws + MR_BYTES + GT_BYTES);

    ln_stats_kernel<<<Bb * Nn / 4, 256, 0, stream>>>(x, mrw);
    gcvt_kernel<<<dim3(16, 8, Bb), 256, 0, stream>>>(x, gamma, beta, mrw, gtw);
    wcvt_kernel<<<dim3(64, 64), 256, 0, stream>>>(w, wtw);
    sgu_mfma_kernel<<<dim3(32, 16), 256, 0, stream>>>(x, wtw, gtw, bias, out);
}

// Round 10
// 214.936 us; speedup vs baseline: 1.1781x; 1.0125x over previous
//
#include <hip/hip_runtime.h>
#include <hip/hip_bf16.h>

// CausalSGU: bf16 pre-pass tiles + global_load_lds MFMA matmul.
// ws: [0,64K) mu/rstd float2 | [64K,+16M) Gt tiles | [+16M,+32M) Wt tiles.
// Tile format (8KB = 512 slots x 16B): slot s -> row r=s>>2, k8 = (s&3)^((r>>1)&3)
// (pre-swizzled LDS image; both-sides-or-neither rule m173/m104).

constexpr int Bb = 4;
constexpr int Nn = 2048;
constexpr int DX = 2048;
constexpr int GD = 1024;   // gate width
constexpr int DH = 256;    // per-head width

typedef short short8v __attribute__((ext_vector_type(8)));
typedef float f32x4   __attribute__((ext_vector_type(4)));

static __device__ __forceinline__ short f2bf(float f) {
    return __builtin_bit_cast(short, __float2bfloat16(f));   // RNE
}

static __device__ __forceinline__ void gll16(const void* g, void* l) {
    __builtin_amdgcn_global_load_lds(
        (const __attribute__((address_space(1))) void*)g,
        (__attribute__((address_space(3))) void*)l, 16, 0, 0);
}

// --- kernel 1: per-row mean/rstd of gate half -> float2 {mu, rstd} ---
__global__ __launch_bounds__(256) void ln_stats_kernel(const float* __restrict__ x,
                                                       float2* __restrict__ mr) {
    int t = threadIdx.x;
    int row = blockIdx.x * 4 + (t >> 6);
    int lane = t & 63;
    const float4* xr = reinterpret_cast<const float4*>(x + (size_t)row * DX + GD);
    float s = 0.f, ss = 0.f;
#pragma unroll
    for (int q = 0; q < 4; ++q) {
        float4 v = xr[q * 64 + lane];
        s  += v.x + v.y + v.z + v.w;
        ss += v.x*v.x + v.y*v.y + v.z*v.z + v.w*v.w;
    }
#pragma unroll
    for (int off = 32; off >= 1; off >>= 1) {
        s  += __shfl_down(s,  off, 64);
        ss += __shfl_down(ss, off, 64);
    }
    if (lane == 0) {
        float m   = s * (1.f / GD);
        float var = ss * (1.f / GD) - m * m;
        mr[row] = make_float2(m, rsqrtf(var + 1e-5f));
    }
}

// --- kernel 2: W fp32 -> Wt bf16 tiles, tril baked. block=(h*16+mt, kt) ---
__global__ __launch_bounds__(256) void wcvt_kernel(const float* __restrict__ w,
                                                   short* __restrict__ wt) {
    const int hm = blockIdx.x;          // h*16 + mt
    const int kt = blockIdx.y;          // 0..63
    const int mt = hm & 15, h = hm >> 4;
    if (kt > 4 * mt + 3) return;        // never read (upper-triangular)
    const int t = threadIdx.x;
    const int m0 = mt * 128, n0 = kt * 32;
    short* tile = wt + ((size_t)hm * 64 + kt) * 4096;
#pragma unroll
    for (int j = 0; j < 2; ++j) {
        int s  = 2 * t + j;
        int r  = s >> 2;
        int k8 = (s & 3) ^ ((r >> 1) & 3);
        const float* src = w + (size_t)(h * Nn + m0 + r) * Nn + n0 + k8 * 8;
        float4 a = *reinterpret_cast<const float4*>(src);
        float4 c = *reinterpret_cast<const float4*>(src + 4);
        const int m = m0 + r, nb0 = n0 + k8 * 8;
        float av[8] = {a.x, a.y, a.z, a.w, c.x, c.y, c.z, c.w};
        short8v o;
#pragma unroll
        for (int e = 0; e < 8; ++e) o[e] = f2bf((nb0 + e) <= m ? av[e] : 0.f);
        *reinterpret_cast<short8v*>(tile + s * 8) = o;
    }
}

// --- kernel 3: gate -> LN -> bf16, transposed [c][n] tiles. block=(nb, cblk, b) ---
__global__ __launch_bounds__(256) void gcvt_kernel(const float* __restrict__ x,
                                                   const float* __restrict__ gamma,
                                                   const float* __restrict__ beta,
                                                   const float2* __restrict__ mr,
                                                   short* __restrict__ gt) {
    __shared__ short T[128 * 136];      // [c][n] bf16, pitch 136
    const int nb = blockIdx.x, cblk = blockIdx.y, b = blockIdx.z;
    const int t = threadIdx.x;
    const int n0b = nb * 128, c0 = cblk * 128;
    const int c4 = (t & 31) * 4, rg = t >> 5;

    const float* src = x + (size_t)b * Nn * DX + GD + c0 + c4;
    float4 gm = *reinterpret_cast<const float4*>(gamma + c0 + c4);
    float4 bt = *reinterpret_cast<const float4*>(beta  + c0 + c4);
    const float2* mrb = mr + b * Nn + n0b;

#pragma unroll
    for (int i = 0; i < 16; ++i) {
        int n = i * 8 + rg;
        float2 ms = mrb[n];
        float4 v  = *reinterpret_cast<const float4*>(src + (size_t)(n0b + n) * DX);
        T[(c4 + 0) * 136 + n] = f2bf((v.x - ms.x) * ms.y * gm.x + bt.x);
        T[(c4 + 1) * 136 + n] = f2bf((v.y - ms.x) * ms.y * gm.y + bt.y);
        T[(c4 + 2) * 136 + n] = f2bf((v.z - ms.x) * ms.y * gm.z + bt.z);
        T[(c4 + 3) * 136 + n] = f2bf((v.w - ms.x) * ms.y * gm.w + bt.w);
    }
    __syncthreads();
#pragma unroll
    for (int kq = 0; kq < 4; ++kq) {
        short* tile = gt + ((size_t)(b * 8 + cblk) * 64 + (nb * 4 + kq)) * 4096;
#pragma unroll
        for (int j = 0; j < 2; ++j) {
            int s  = 2 * t + j;
            int c  = s >> 2;
            int n8 = (s & 3) ^ ((c >> 1) & 3);
            short8v v = *reinterpret_cast<const short8v*>(&T[c * 136 + kq * 32 + n8 * 8]);
            *reinterpret_cast<short8v*>(tile + s * 8) = v;
        }
    }
}

// --- kernel 4: causal MFMA matmul, 128x64 blocks, XCD-chunked + work-balanced ---
__global__ __launch_bounds__(256, 4) void sgu_mfma_kernel(
    const float* __restrict__ x, const short* __restrict__ wt,
    const short* __restrict__ gt, const float* __restrict__ bias,
    float* __restrict__ out)
{
    __shared__ __align__(16) short WS[2][4096];   // 8KB W tile
    __shared__ __align__(16) short GS[2][2048];   // 4KB G half-tile

    const int t  = threadIdx.x;
    const int id = blockIdx.x;              // 0..1023
    // chunk c (ids [c*128,(c+1)*128)) -> XCD c (round-robin dispatch):
    //   first 64 ids: heavy mt = 15-c, next 64: light mt = c.
    //   Every chunk/CU gets mt-pair summing to 15 -> 136 k-tiles/CU uniform;
    //   all 16 sharers of a Wt tile (4b x 4dcq) live in one chunk -> L2 reuse.
    const int xcd  = id >> 7;
    const int half = (id >> 6) & 1;
    const int xc   = id & 63;               // b(4) | h(4) | dcq(4)
    const int mt   = half ? xcd : 15 - xcd;
    const int dcq  = xc & 3;
    const int h    = (xc >> 2) & 3;
    const int b    = xc >> 4;
    const int m0 = mt * 128;
    const int cb = h * DH + dcq * 64;       // channel base in [0,1024)
    const int nk = 4 * mt + 4;              // causal k-tiles

    const int lane = t & 63;
    const int wv = t >> 6;
    const int wm = wv >> 1, wc = wv & 1;    // 2x2 waves: 64m x 32c each
    const int g  = lane >> 4;               // k-slice group
    const int lr = lane & 15;

    const char* wtb = (const char*)wt + ((size_t)(h * 16 + mt) * 64) * 8192;
    const char* gtb = (const char*)gt
        + ((size_t)(b * 8 + h * 2 + (dcq >> 1)) * 64) * 8192 + (dcq & 1) * 4096;
    const int wsoff = wv * 2048 + lane * 16;
    const int gsoff = wv * 1024 + lane * 16;

    f32x4 acc[4][2] = {};

    auto STAGE = [&](int buf, int kt) {
        const char* ws = wtb + (size_t)kt * 8192 + wsoff;
        const char* gs = gtb + (size_t)kt * 8192 + gsoff;
        short* wd = &WS[buf][wv * 1024];    // wave-uniform LDS base
        short* gd = &GS[buf][wv * 512];
        gll16(ws,        wd);
        gll16(ws + 1024, wd + 512);
        gll16(gs,        gd);
    };

    auto COMPUTE = [&](int buf) {
        const char* wl = (const char*)&WS[buf][0];
        const char* gl = (const char*)&GS[buf][0];
        short8v af[4], bf[2];
#pragma unroll
        for (int fi = 0; fi < 4; ++fi) {
            int row = wm * 64 + fi * 16 + lr;
            unsigned off = (unsigned)(row * 64 + g * 16);
            off ^= ((unsigned)(row >> 1) & 3u) << 4;
            af[fi] = *reinterpret_cast<const short8v*>(wl + off);
        }
#pragma unroll
        for (int fj = 0; fj < 2; ++fj) {
            int rp = wc * 32 + fj * 16 + lr;    // row within 64-row half-tile
            unsigned off = (unsigned)(rp * 64 + g * 16);
            off ^= ((unsigned)(rp >> 1) & 3u) << 4;
            bf[fj] = *reinterpret_cast<const short8v*>(gl + off);
        }
#pragma unroll
        for (int fi = 0; fi < 4; ++fi)
#pragma unroll
            for (int fj = 0; fj < 2; ++fj)
                acc[fi][fj] = __builtin_amdgcn_mfma_f32_16x16x32_bf16(
                    af[fi], bf[fj], acc[fi][fj], 0, 0, 0);
    };

    STAGE(0, 0);
    __syncthreads();
    int cur = 0;
    for (int kt = 0; kt < nk; ++kt) {
        if (kt + 1 < nk) STAGE(cur ^ 1, kt + 1);
        COMPUTE(cur);
        __syncthreads();
        cur ^= 1;
    }

    const float* xb = x + (size_t)b * Nn * DX;
#pragma unroll
    for (int fi = 0; fi < 4; ++fi) {
#pragma unroll
        for (int r = 0; r < 4; ++r) {
            int m = m0 + wm * 64 + fi * 16 + g * 4 + r;
            float bv = bias[h * Nn + m];
            const float* resrow = xb + (size_t)m * DX + cb;
            float* orow = out + ((size_t)b * Nn + m) * GD + cb;
#pragma unroll
            for (int fj = 0; fj < 2; ++fj) {
                int c = wc * 32 + fj * 16 + lr;
                orow[c] = (acc[fi][fj][r] + bv) * resrow[c];
            }
        }
    }
}

extern "C" void kernel_launch(void* const* d_in, const int* in_sizes, int n_in,
                              void* d_out, int out_size, void* d_ws, size_t ws_size,
                              hipStream_t stream) {
    const float* x     = (const float*)d_in[0];
    const float* w     = (const float*)d_in[1];
    const float* bias  = (const float*)d_in[2];
    const float* gamma = (const float*)d_in[3];
    const float* beta  = (const float*)d_in[4];
    float* out = (float*)d_out;

    const size_t MR_BYTES = 64 * 1024;
    const size_t GT_BYTES = (size_t)16 * 1024 * 1024;
    const size_t WT_BYTES = (size_t)32 * 1024 * 1024;
    if (ws_size < MR_BYTES + GT_BYTES + WT_BYTES) return;

    float2* mrw = (float2*)d_ws;
    short*  gtw = (short*)((char*)d_ws + MR_BYTES);
    short*  wtw = (short*)((char*)d_ws + MR_BYTES + GT_BYTES);

    ln_stats_kernel<<<Bb * Nn / 4, 256, 0, stream>>>(x, mrw);
    gcvt_kernel<<<dim3(16, 8, Bb), 256, 0, stream>>>(x, gamma, beta, mrw, gtw);
    wcvt_kernel<<<dim3(64, 64), 256, 0, stream>>>(w, wtw);
    sgu_mfma_kernel<<<1024, 256, 0, stream>>>(x, wtw, gtw, bias, out);
}